// Round 5
// baseline (967.324 us; speedup 1.0000x reference)
//
#include <hip/hip_runtime.h>
#include <stdint.h>

// Problem constants (fixed by setup_inputs)
#define B_ 64
#define C_ 256
#define H_ 56
#define W_ 56
#define HM 50              // H - (BLOCK_SIZE-1)
#define WM 50
#define NPLANES (B_ * C_)          // 16384
#define PLANE_IN (HM * WM)         // 2500
#define PLANE_OUT (H_ * W_)        // 3136
#define NTOT (NPLANES * PLANE_OUT) // 51,380,224

#define PPB 16                     // planes per block
#define DGRID (NPLANES / PPB)      // 1024 blocks
#define BQ (PPB * PLANE_OUT / 4)   // 12544 float4 per block's x/out slice
#define KW (PPB * H_)              // 896 keep-mask words per block (LDS)
#define READY 0x80000000u

typedef float f4 __attribute__((ext_vector_type(4)));

// Single fused kernel, NO cooperative API (R4 lesson: 2048-block cooperative
// launch at exact-max occupancy was rejected -> silent all-zero output).
// Grid-wide sync is a ready-bit spin barrier, safe by CAPACITY arithmetic:
//   1024 blocks, __launch_bounds__(256,4) => >=4 blocks/CU co-resident
//   (256 CU x 4 = 1024), using only HALF the 2048-thread/CU hardware limit;
//   LDS 7.4 KB/block (x4 = 30 KB of 160). All blocks are resident before any
//   spins, so the barrier cannot deadlock. Cross-XCD visibility via
//   device-scope (AGENT) atomic store/load per guide G16.
// [R1 lesson: NO single-address global atomics — they serialize ~12 ns/op.]
__global__ __launch_bounds__(256, 4) void fused_kernel(
        const float* __restrict__ u,
        const float* __restrict__ gamma,
        const float* __restrict__ x,
        float* __restrict__ out,
        unsigned int* blocksum) {      // [DGRID], pre-zeroed each iteration
    __shared__ unsigned long long hdil[2][HM];   // 800 B, double-buffered
    __shared__ unsigned long long keep[KW];      // 7168 B
    __shared__ unsigned int sred[4];
    __shared__ float s_scale;

    const int tid  = threadIdx.x;
    const int wave = tid >> 6;
    const int lane = tid & 63;
    const float g  = gamma[0];

    unsigned int blockTotal = 0;   // meaningful on (wave 0, lane 0) only

    // ---------------- Phase 1: dilate 16 planes (verified R3 logic) -------
    #pragma unroll 1
    for (int k = 0; k < PPB; ++k) {
        const int plane = blockIdx.x * PPB + k;    // contiguous u streaming
        const float* up = u + (size_t)plane * PLANE_IN;
        unsigned long long* hd = hdil[k & 1];

        // Rows r = wave + 4*i; lanes 0..49 load row floats, ballot packs
        // the seed predicate into a 64-bit row mask in one instruction.
        #pragma unroll
        for (int i = 0; i < 13; ++i) {
            int r = wave + 4 * i;
            float v = 1e30f;                  // predicate false for idle lanes
            if (r < HM && lane < WM) v = up[r * WM + lane];
            unsigned long long bits = __ballot(v < g);
            // horizontal dilation: OR of shifts 0..6 via log-step smear
            unsigned long long h = bits | (bits << 1);
            h |= h << 2;
            h |= h << 3;
            if (lane == 0 && r < HM) hd[r] = h;
        }
        __syncthreads();
        // Waves 1-3 run ahead into plane k+1 (buffer (k+1)&1) while wave 0
        // finishes this plane's epilogue; plane k+2 can only re-write this
        // buffer after barrier k+1 orders wave 0's reads first. Race-free.

        unsigned int zcnt = 0;
        if (tid < H_) {
            int r0 = tid - 6; if (r0 < 0) r0 = 0;
            int r1 = tid;     if (r1 > HM - 1) r1 = HM - 1;
            unsigned long long v = 0ull;
            for (int r = r0; r <= r1; ++r) v |= hd[r];
            unsigned long long kmask = (~v) & ((1ULL << W_) - 1ULL);
            keep[k * H_ + tid] = kmask;
            zcnt = (unsigned int)__popcll(kmask);
        }
        if (wave == 0) {                 // threads 0..55 all live in wave 0
            #pragma unroll
            for (int off = 32; off > 0; off >>= 1)
                zcnt += __shfl_down(zcnt, off, 64);
            blockTotal += zcnt;          // lane 0 holds the true sum
        }
    }
    if (tid == 0)
        __hip_atomic_store(&blocksum[blockIdx.x], blockTotal | READY,
                           __ATOMIC_RELEASE, __HIP_MEMORY_SCOPE_AGENT);

    // ------- Phase 2: spin-gather all per-block totals -> scale -----------
    // Work is identical across blocks, so arrival skew (and spin time) is
    // tiny. 1024 words, LLC-hot; 4 entries/thread.
    unsigned int sum = 0;
    #pragma unroll
    for (int j = 0; j < DGRID / 256; ++j) {
        const int idx = tid + j * 256;
        unsigned int v;
        do {
            v = __hip_atomic_load(&blocksum[idx], __ATOMIC_ACQUIRE,
                                  __HIP_MEMORY_SCOPE_AGENT);
        } while (!(v & READY));
        sum += (v & ~READY);
    }
    #pragma unroll
    for (int off = 32; off > 0; off >>= 1)
        sum += __shfl_down(sum, off, 64);
    if (lane == 0) sred[wave] = sum;
    __syncthreads();                     // also orders keep[] for phase 3
    if (tid == 0)
        s_scale = (float)NTOT /
                  (float)(sred[0] + sred[1] + sred[2] + sred[3]);
    __syncthreads();
    const float scale = s_scale;

    // ---------------- Phase 3: apply to own 16 planes ---------------------
    // ~63% of pixels are dropped (gamma=0.02, 7x7 dilation, keep=.98^49) in
    // >=7-wide runs: predicated NT x-load skips HBM fetch for fully-dropped
    // quads/lines. NT store: out streamed once. Mask comes from LDS.
    const f4* xp = (const f4*)x   + (size_t)blockIdx.x * BQ;
    f4*       op = (f4*)      out + (size_t)blockIdx.x * BQ;
    #pragma unroll 1
    for (int i = tid; i < BQ; i += 256) {
        int word = i / 14;               // local row index (W_/4 == 14)
        int w4   = i - word * 14;
        unsigned int bits = (unsigned int)(keep[word] >> (w4 * 4)) & 0xFu;
        f4 o = {0.0f, 0.0f, 0.0f, 0.0f};
        if (bits) {                      // skip x fetch for fully-dropped quads
            f4 v = __builtin_nontemporal_load(&xp[i]);
            o.x = (bits & 1u) ? v.x * scale : 0.0f;
            o.y = (bits & 2u) ? v.y * scale : 0.0f;
            o.z = (bits & 4u) ? v.z * scale : 0.0f;
            o.w = (bits & 8u) ? v.w * scale : 0.0f;
        }
        __builtin_nontemporal_store(o, &op[i]);
    }
}

extern "C" void kernel_launch(void* const* d_in, const int* in_sizes, int n_in,
                              void* d_out, int out_size, void* d_ws, size_t ws_size,
                              hipStream_t stream) {
    const float* x     = (const float*)d_in[0];
    const float* u     = (const float*)d_in[1];
    const float* gamma = (const float*)d_in[2];
    float* out = (float*)d_out;

    // Workspace: [1024, 1024+4KB) per-block ready|count words.
    unsigned int* blocksum = (unsigned int*)((char*)d_ws + 1024);

    // Re-arm the ready bits every graph iteration (4 KB, ~1 us).
    hipMemsetAsync(blocksum, 0, DGRID * sizeof(unsigned int), stream);
    fused_kernel<<<DGRID, 256, 0, stream>>>(u, gamma, x, out, blocksum);
}